// Round 1
// baseline (1326.344 us; speedup 1.0000x reference)
//
#include <hip/hip_runtime.h>
#include <hip/hip_bf16.h>

// Problem constants (from reference)
#define S_DIM 8192
#define H_DIM 7168
#define D0_DIM 1536
#define D1_DIM 576
#define N_DIM 2112          // D0 + D1
#define R_DIM 64
#define LA_WIDTH 128        // 2 * R

typedef __attribute__((ext_vector_type(4))) float f32x4;
typedef __attribute__((ext_vector_type(8))) short bf16x8;
typedef __attribute__((ext_vector_type(4))) short bf16x4;

__device__ __forceinline__ short f2bf(float f) {
    union { __hip_bfloat16 h; short s; } u;
    u.h = __float2bfloat16(f);
    return u.s;
}

__device__ __forceinline__ bf16x8 pack8(f32x4 a, f32x4 b) {
    bf16x8 r;
    r[0] = f2bf(a[0]); r[1] = f2bf(a[1]); r[2] = f2bf(a[2]); r[3] = f2bf(a[3]);
    r[4] = f2bf(b[0]); r[5] = f2bf(b[1]); r[6] = f2bf(b[2]); r[7] = f2bf(b[3]);
    return r;
}

// ---------------------------------------------------------------------------
// Pass 1: la[S, 128] = x[S, H] @ A_buffer[128, H]^T      (fp32 out into d_ws)
// M-tile = 32, N = 128 (full), BK = 32. 256 blocks, 256 threads (4 waves).
// Wave w computes cols [w*32, w*32+32): 2x2 grid of 16x16 MFMA tiles.
// ---------------------------------------------------------------------------
__global__ __launch_bounds__(256, 2)
void lora_a_gemm(const float* __restrict__ x, const float* __restrict__ Abuf,
                 float* __restrict__ la) {
    __shared__ __align__(16) short sX[32 * 40];
    __shared__ __align__(16) short sA[128 * 40];

    const int tid = threadIdx.x;
    const int m0 = blockIdx.x * 32;
    const int wave = tid >> 6;
    const int lane = tid & 63;
    const int fr = lane & 15;
    const int fq = lane >> 4;
    const int wn = wave * 32;

    f32x4 acc[2][2] = {};

    // staging: x tile 32x32 (1 float4/thread), A tile 128x32 (16 floats/thread)
    const int xrow = tid >> 3, xcol = (tid & 7) * 4;
    const float* xP = x + (size_t)(m0 + xrow) * H_DIM + xcol;
    short* sXw = sX + xrow * 40 + xcol;

    const int arow = tid >> 1, ahalf = (tid & 1) * 16;
    const float* aP = Abuf + (size_t)arow * H_DIM + ahalf;
    short* sAw = sA + arow * 40 + ahalf;

    const short* sXr = sX + fr * 40 + fq * 8;
    const short* sAr = sA + (wn + fr) * 40 + fq * 8;

    for (int kt = 0; kt < H_DIM / 32; ++kt) {
        f32x4 xv = *(const f32x4*)(xP + kt * 32);
        f32x4 a0 = *(const f32x4*)(aP + kt * 32);
        f32x4 a1 = *(const f32x4*)(aP + kt * 32 + 4);
        f32x4 a2 = *(const f32x4*)(aP + kt * 32 + 8);
        f32x4 a3 = *(const f32x4*)(aP + kt * 32 + 12);

        bf16x4 xs;
        xs[0] = f2bf(xv[0]); xs[1] = f2bf(xv[1]);
        xs[2] = f2bf(xv[2]); xs[3] = f2bf(xv[3]);
        bf16x8 as0 = pack8(a0, a1), as1 = pack8(a2, a3);

        __syncthreads();
        *(bf16x4*)(sXw) = xs;
        *(bf16x8*)(sAw) = as0;
        *(bf16x8*)(sAw + 8) = as1;
        __syncthreads();

        bf16x8 xf0 = *(const bf16x8*)(sXr);
        bf16x8 xf1 = *(const bf16x8*)(sXr + 16 * 40);
        bf16x8 af0 = *(const bf16x8*)(sAr);
        bf16x8 af1 = *(const bf16x8*)(sAr + 16 * 40);

        acc[0][0] = __builtin_amdgcn_mfma_f32_16x16x32_bf16(xf0, af0, acc[0][0], 0, 0, 0);
        acc[0][1] = __builtin_amdgcn_mfma_f32_16x16x32_bf16(xf0, af1, acc[0][1], 0, 0, 0);
        acc[1][0] = __builtin_amdgcn_mfma_f32_16x16x32_bf16(xf1, af0, acc[1][0], 0, 0, 0);
        acc[1][1] = __builtin_amdgcn_mfma_f32_16x16x32_bf16(xf1, af1, acc[1][1], 0, 0, 0);
    }

#pragma unroll
    for (int ni = 0; ni < 2; ++ni) {
        const int col = wn + ni * 16 + fr;
#pragma unroll
        for (int mi = 0; mi < 2; ++mi) {
            const int row = m0 + mi * 16 + fq * 4;
#pragma unroll
            for (int r = 0; r < 4; ++r)
                la[(size_t)(row + r) * LA_WIDTH + col] = acc[mi][ni][r];
        }
    }
}

// ---------------------------------------------------------------------------
// Pass 2: out[S, 2112] = x @ W^T + bias + la @ B_slice^T (LoRA fused as 2
// extra K-iterations). 128x128 tile, BK=32, 16x16x32 bf16 MFMA.
// 4 waves in 2x2, each 64x64 (4x4 fragments). Grid (17, 64), bn-fast for
// Infinity-Cache-friendly working set.
// ---------------------------------------------------------------------------
#define LDS_STRIDE 40

__global__ __launch_bounds__(256, 2)
void main_gemm(const float* __restrict__ x, const float* __restrict__ W,
               const float* __restrict__ bias, const float* __restrict__ Bbuf,
               const float* __restrict__ la, float* __restrict__ out) {
    __shared__ __align__(16) short sA[128 * LDS_STRIDE];
    __shared__ __align__(16) short sB[128 * LDS_STRIDE];

    const int tid = threadIdx.x;
    const int bn = blockIdx.x;          // 0..16
    const int bm = blockIdx.y;          // 0..63
    const int m0 = bm * 128, n0 = bn * 128;

    const int wave = tid >> 6;
    const int lane = tid & 63;
    const int wm = (wave & 1) * 64;
    const int wn = (wave >> 1) * 64;
    const int fr = lane & 15;
    const int fq = lane >> 4;

    f32x4 acc[4][4] = {};

    // staging: each thread loads 16 consecutive floats of one row
    const int srow = tid >> 1;
    const int shalf = (tid & 1) * 16;

    const float* xP = x + (size_t)(m0 + srow) * H_DIM + shalf;
    const int wRow = n0 + srow;
    const bool wValid = wRow < N_DIM;
    const float* wP = W + (size_t)wRow * H_DIM + shalf;

    // LoRA segment (uniform per block: n-tiles 0..11 -> slice 0, 12..16 -> slice 1)
    const int slice = (n0 >= D0_DIM) ? 1 : 0;
    const int oCol = wRow - slice * D0_DIM;
    const bool bValid = wValid && (oCol < (slice ? D1_DIM : D0_DIM));
    const float* laP = la + (size_t)(m0 + srow) * LA_WIDTH + slice * R_DIM + shalf;
    const float* bP = Bbuf + ((size_t)slice * D0_DIM + oCol) * R_DIM + shalf;

    short* sAw = sA + srow * LDS_STRIDE + shalf;
    short* sBw = sB + srow * LDS_STRIDE + shalf;

    const short* sAr = sA + (wm + fr) * LDS_STRIDE + fq * 8;
    const short* sBr = sB + (wn + fr) * LDS_STRIDE + fq * 8;

    const int KT = H_DIM / 32;          // 224
    for (int it = 0; it < KT + 2; ++it) {
        const float* pa;
        const float* pb;
        bool vb;
        if (it < KT) {
            pa = xP + it * 32;
            pb = wP + it * 32;
            vb = wValid;
        } else {
            const int lt = it - KT;
            pa = laP + lt * 32;
            pb = bP + lt * 32;
            vb = bValid;
        }

        f32x4 a0 = *(const f32x4*)(pa);
        f32x4 a1 = *(const f32x4*)(pa + 4);
        f32x4 a2 = *(const f32x4*)(pa + 8);
        f32x4 a3 = *(const f32x4*)(pa + 12);
        f32x4 z = {0.f, 0.f, 0.f, 0.f};
        f32x4 b0 = z, b1 = z, b2 = z, b3 = z;
        if (vb) {
            b0 = *(const f32x4*)(pb);
            b1 = *(const f32x4*)(pb + 4);
            b2 = *(const f32x4*)(pb + 8);
            b3 = *(const f32x4*)(pb + 12);
        }
        bf16x8 pa0 = pack8(a0, a1), pa1 = pack8(a2, a3);
        bf16x8 pb0 = pack8(b0, b1), pb1 = pack8(b2, b3);

        __syncthreads();
        *(bf16x8*)(sAw) = pa0;
        *(bf16x8*)(sAw + 8) = pa1;
        *(bf16x8*)(sBw) = pb0;
        *(bf16x8*)(sBw + 8) = pb1;
        __syncthreads();

        bf16x8 af[4], bfg[4];
#pragma unroll
        for (int i = 0; i < 4; ++i) af[i] = *(const bf16x8*)(sAr + i * 16 * LDS_STRIDE);
#pragma unroll
        for (int i = 0; i < 4; ++i) bfg[i] = *(const bf16x8*)(sBr + i * 16 * LDS_STRIDE);
#pragma unroll
        for (int mi = 0; mi < 4; ++mi)
#pragma unroll
            for (int ni = 0; ni < 4; ++ni)
                acc[mi][ni] = __builtin_amdgcn_mfma_f32_16x16x32_bf16(
                    af[mi], bfg[ni], acc[mi][ni], 0, 0, 0);
    }

    // epilogue: + bias, store fp32. C/D layout: col = lane&15, row = fq*4 + r
#pragma unroll
    for (int ni = 0; ni < 4; ++ni) {
        const int col = n0 + wn + ni * 16 + fr;
        if (col < N_DIM) {
            const float bv = bias[col];
#pragma unroll
            for (int mi = 0; mi < 4; ++mi) {
                const int row = m0 + wm + mi * 16 + fq * 4;
#pragma unroll
                for (int r = 0; r < 4; ++r)
                    out[(size_t)(row + r) * N_DIM + col] = acc[mi][ni][r] + bv;
            }
        }
    }
}

extern "C" void kernel_launch(void* const* d_in, const int* in_sizes, int n_in,
                              void* d_out, int out_size, void* d_ws, size_t ws_size,
                              hipStream_t stream) {
    const float* x    = (const float*)d_in[0];
    const float* W    = (const float*)d_in[1];
    const float* bias = (const float*)d_in[2];
    const float* A    = (const float*)d_in[3];
    const float* B    = (const float*)d_in[4];
    float* out = (float*)d_out;
    float* la  = (float*)d_ws;   // 8192*128 fp32 = 4 MB scratch

    lora_a_gemm<<<dim3(S_DIM / 32), dim3(256), 0, stream>>>(x, A, la);
    main_gemm<<<dim3(N_DIM / 128 + 1, S_DIM / 128), dim3(256), 0, stream>>>(
        x, W, bias, B, la, out);
}

// Round 2
// 980.995 us; speedup vs baseline: 1.3520x; 1.3520x over previous
//
#include <hip/hip_runtime.h>
#include <hip/hip_bf16.h>

// Problem constants (from reference)
#define S_DIM 8192
#define H_DIM 7168
#define D0_DIM 1536
#define D1_DIM 576
#define N_DIM 2112          // D0 + D1
#define R_DIM 64
#define LA_WIDTH 128        // 2 * R

// Extended-K fused layout: K' = H + 128 (64 lora cols per slice, complementary
// halves zeroed in Wext so one GEMM computes base + LoRA-B contribution).
#define K_EXT 7296
#define KT_EXT 228          // K_EXT / 32
#define N_PAD 2176          // 17 * 128 (Wext padded rows; cols >= N_DIM masked at store)

typedef __attribute__((ext_vector_type(4))) float f32x4;
typedef __attribute__((ext_vector_type(8))) short bf16x8;
typedef __attribute__((ext_vector_type(4))) short bf16x4;

__device__ __forceinline__ short f2bf(float f) {
    union { __hip_bfloat16 h; short s; } u;
    u.h = __float2bfloat16(f);
    return u.s;
}

__device__ __forceinline__ bf16x8 pack8(f32x4 a, f32x4 b) {
    bf16x8 r;
    r[0] = f2bf(a[0]); r[1] = f2bf(a[1]); r[2] = f2bf(a[2]); r[3] = f2bf(a[3]);
    r[4] = f2bf(b[0]); r[5] = f2bf(b[1]); r[6] = f2bf(b[2]); r[7] = f2bf(b[3]);
    return r;
}

__device__ __forceinline__ void gload_lds16(const short* g, short* l) {
    __builtin_amdgcn_global_load_lds(
        (const __attribute__((address_space(1))) unsigned int*)(const void*)g,
        (__attribute__((address_space(3))) unsigned int*)(void*)l, 16, 0, 0);
}

// ---------------------------------------------------------------------------
// convert_x: x fp32 [S,H] -> xext bf16 [S,K_EXT] cols 0..H  (8 elems/thread)
// ---------------------------------------------------------------------------
__global__ __launch_bounds__(256)
void convert_x(const float* __restrict__ x, short* __restrict__ xe) {
    unsigned id = blockIdx.x * 256u + threadIdx.x;   // < 8192*896
    unsigned row = id / 896u, col = (id % 896u) * 8u;
    const float* p = x + (size_t)row * H_DIM + col;
    f32x4 a = *(const f32x4*)p;
    f32x4 b = *(const f32x4*)(p + 4);
    *(bf16x8*)(xe + (size_t)row * K_EXT + col) = pack8(a, b);
}

// convert_w: W fp32 [N,H] -> Wext bf16 [N_PAD,K_EXT] cols 0..H
__global__ __launch_bounds__(256)
void convert_w(const float* __restrict__ W, short* __restrict__ we) {
    unsigned id = blockIdx.x * 256u + threadIdx.x;   // < 2112*896
    unsigned row = id / 896u, col = (id % 896u) * 8u;
    const float* p = W + (size_t)row * H_DIM + col;
    f32x4 a = *(const f32x4*)p;
    f32x4 b = *(const f32x4*)(p + 4);
    *(bf16x8*)(we + (size_t)row * K_EXT + col) = pack8(a, b);
}

// convert_w_lora: fill Wext cols H..H+128 per row n:
//   n <  D0: [B0 row n (64), zeros(64)]
//   n >= D0: [zeros(64), B1 row n-D0 (64)]   (n-D0 < 576 always since N=2112)
__global__ __launch_bounds__(256)
void convert_w_lora(const float* __restrict__ Bbuf, short* __restrict__ we) {
    unsigned id = blockIdx.x * 256u + threadIdx.x;   // < 2112*16
    unsigned n = id / 16u, c8 = (id % 16u) * 8u;     // c8 in {0..120}
    const bool slice1 = n >= D0_DIM;
    bf16x8 v = {};
    const bool dataHalf = slice1 ? (c8 >= 64u) : (c8 < 64u);
    if (dataHalf) {
        unsigned bi = slice1 ? 1u : 0u;
        unsigned brow = slice1 ? (n - D0_DIM) : n;
        unsigned bcol = slice1 ? (c8 - 64u) : c8;
        const float* p = Bbuf + ((size_t)bi * D0_DIM + brow) * R_DIM + bcol;
        f32x4 a = *(const f32x4*)p;
        f32x4 b = *(const f32x4*)(p + 4);
        v = pack8(a, b);
    }
    *(bf16x8*)(we + (size_t)n * K_EXT + H_DIM + c8) = v;
}

// convert_a: A fp32 [128,H] -> Aext bf16 [128,H]
__global__ __launch_bounds__(256)
void convert_a(const float* __restrict__ A, short* __restrict__ ae) {
    unsigned id = blockIdx.x * 256u + threadIdx.x;   // < 128*896
    unsigned row = id / 896u, col = (id % 896u) * 8u;
    const float* p = A + (size_t)row * H_DIM + col;
    f32x4 a = *(const f32x4*)p;
    f32x4 b = *(const f32x4*)(p + 4);
    *(bf16x8*)(ae + (size_t)row * H_DIM + col) = pack8(a, b);
}

// ---------------------------------------------------------------------------
// lora_a_fast: la[S,128] = x @ A^T (bf16 in, bf16 out into xext cols H..H+128)
// M-tile 32, full N=128, BK=32; 256 blocks x 256 threads (4 waves, 32 cols each)
// ---------------------------------------------------------------------------
__global__ __launch_bounds__(256, 2)
void lora_a_fast(const short* __restrict__ xe, const short* __restrict__ ae,
                 short* __restrict__ xe_out) {
    __shared__ __align__(16) short sX[32 * 40];
    __shared__ __align__(16) short sA[128 * 40];

    const int tid = threadIdx.x;
    const int m0 = blockIdx.x * 32;
    const int wave = tid >> 6, lane = tid & 63;
    const int fr = lane & 15, fq = lane >> 4;
    const int wn = wave * 32;

    f32x4 acc[2][2] = {};

    const int xrow = tid >> 2, xcol = (tid & 3) * 8;           // tid<128 stages x
    const short* xP = xe + (size_t)(m0 + xrow) * K_EXT + xcol;
    short* sXw = sX + xrow * 40 + xcol;

    const int arow = tid >> 1, acol = (tid & 1) * 16;          // 2x8 elems each
    const short* aP = ae + (size_t)arow * H_DIM + acol;
    short* sAw = sA + arow * 40 + acol;

    const short* sXr = sX + fr * 40 + fq * 8;
    const short* sAr = sA + (wn + fr) * 40 + fq * 8;

    for (int kt = 0; kt < H_DIM / 32; ++kt) {
        bf16x8 xv = {};
        if (tid < 128) xv = *(const bf16x8*)(xP + kt * 32);
        bf16x8 a0 = *(const bf16x8*)(aP + kt * 32);
        bf16x8 a1 = *(const bf16x8*)(aP + kt * 32 + 8);

        __syncthreads();
        if (tid < 128) *(bf16x8*)sXw = xv;
        *(bf16x8*)sAw = a0;
        *(bf16x8*)(sAw + 8) = a1;
        __syncthreads();

        bf16x8 xf0 = *(const bf16x8*)(sXr);
        bf16x8 xf1 = *(const bf16x8*)(sXr + 16 * 40);
        bf16x8 af0 = *(const bf16x8*)(sAr);
        bf16x8 af1 = *(const bf16x8*)(sAr + 16 * 40);

        acc[0][0] = __builtin_amdgcn_mfma_f32_16x16x32_bf16(xf0, af0, acc[0][0], 0, 0, 0);
        acc[0][1] = __builtin_amdgcn_mfma_f32_16x16x32_bf16(xf0, af1, acc[0][1], 0, 0, 0);
        acc[1][0] = __builtin_amdgcn_mfma_f32_16x16x32_bf16(xf1, af0, acc[1][0], 0, 0, 0);
        acc[1][1] = __builtin_amdgcn_mfma_f32_16x16x32_bf16(xf1, af1, acc[1][1], 0, 0, 0);
    }

#pragma unroll
    for (int ni = 0; ni < 2; ++ni) {
        const int col = wn + ni * 16 + fr;                     // 0..127
#pragma unroll
        for (int mi = 0; mi < 2; ++mi) {
            const int row = m0 + mi * 16 + fq * 4;
#pragma unroll
            for (int r = 0; r < 4; ++r)
                xe_out[(size_t)(row + r) * K_EXT + H_DIM + col] = f2bf(acc[mi][ni][r]);
        }
    }
}

// ---------------------------------------------------------------------------
// main_gemm_fast: out = xext @ Wext^T + bias  (K = 7296 includes LoRA-B)
// m97 structure: 128x128 tile, BK=32, global_load_lds width 16, unpadded LDS.
// 4 waves 2x2, each 64x64 (4x4 of 16x16x32 bf16 MFMA).
// ---------------------------------------------------------------------------
__global__ __launch_bounds__(256, 3)
void main_gemm_fast(const short* __restrict__ xe, const short* __restrict__ we,
                    const float* __restrict__ bias, float* __restrict__ out) {
    __shared__ __align__(16) short sX[128 * 32];
    __shared__ __align__(16) short sW[128 * 32];

    const int tid = threadIdx.x;
    const int n0 = blockIdx.x * 128;    // 0..16 -> cols
    const int m0 = blockIdx.y * 128;    // 0..63 -> rows
    const int wave = tid >> 6, lane = tid & 63;
    const int wm = (wave & 1) * 64, wn = (wave >> 1) * 64;
    const int fr = lane & 15, fq = lane >> 4;

    f32x4 acc[4][4] = {};

    // staging: chunk q covers 16 rows (512 elems); lane i: row q*16+i/4, col (i%4)*8
    const int r0 = wave * 16 + (lane >> 2);
    const int c0 = (lane & 3) * 8;
    const short* gx0 = xe + (size_t)(m0 + r0) * K_EXT + c0;
    const short* gx1 = xe + (size_t)(m0 + r0 + 64) * K_EXT + c0;
    const short* gw0 = we + (size_t)(n0 + r0) * K_EXT + c0;
    const short* gw1 = we + (size_t)(n0 + r0 + 64) * K_EXT + c0;
    short* lx0 = sX + wave * 512;          // wave-uniform LDS bases
    short* lx1 = sX + (wave + 4) * 512;
    short* lw0 = sW + wave * 512;
    short* lw1 = sW + (wave + 4) * 512;

    const short* sXr = sX + (wm + fr) * 32 + fq * 8;
    const short* sWr = sW + (wn + fr) * 32 + fq * 8;

    for (int kt = 0; kt < KT_EXT; ++kt) {
        const int ko = kt * 32;
        __syncthreads();                       // prev tile's ds_reads complete
        gload_lds16(gx0 + ko, lx0);
        gload_lds16(gx1 + ko, lx1);
        gload_lds16(gw0 + ko, lw0);
        gload_lds16(gw1 + ko, lw1);
        __syncthreads();                       // drains vmcnt -> tile in LDS

        bf16x8 af[4], bfg[4];
#pragma unroll
        for (int i = 0; i < 4; ++i) af[i] = *(const bf16x8*)(sXr + i * 16 * 32);
#pragma unroll
        for (int i = 0; i < 4; ++i) bfg[i] = *(const bf16x8*)(sWr + i * 16 * 32);
#pragma unroll
        for (int mi = 0; mi < 4; ++mi)
#pragma unroll
            for (int ni = 0; ni < 4; ++ni)
                acc[mi][ni] = __builtin_amdgcn_mfma_f32_16x16x32_bf16(
                    af[mi], bfg[ni], acc[mi][ni], 0, 0, 0);
    }

    // epilogue: + bias, fp32 store. C/D: col = lane&15, row = fq*4 + r
#pragma unroll
    for (int ni = 0; ni < 4; ++ni) {
        const int col = n0 + wn + ni * 16 + fr;
        if (col < N_DIM) {
            const float bv = bias[col];
#pragma unroll
            for (int mi = 0; mi < 4; ++mi) {
                const int row = m0 + wm + mi * 16 + fq * 4;
#pragma unroll
                for (int r = 0; r < 4; ++r)
                    out[(size_t)(row + r) * N_DIM + col] = acc[mi][ni][r] + bv;
            }
        }
    }
}

// ===========================================================================
// Fallback (round-1 proven path) if workspace is too small for bf16 staging
// ===========================================================================
__global__ __launch_bounds__(256, 2)
void lora_a_gemm(const float* __restrict__ x, const float* __restrict__ Abuf,
                 float* __restrict__ la) {
    __shared__ __align__(16) short sX[32 * 40];
    __shared__ __align__(16) short sA[128 * 40];
    const int tid = threadIdx.x;
    const int m0 = blockIdx.x * 32;
    const int wave = tid >> 6, lane = tid & 63;
    const int fr = lane & 15, fq = lane >> 4;
    const int wn = wave * 32;
    f32x4 acc[2][2] = {};
    const int xrow = tid >> 3, xcol = (tid & 7) * 4;
    const float* xP = x + (size_t)(m0 + xrow) * H_DIM + xcol;
    short* sXw = sX + xrow * 40 + xcol;
    const int arow = tid >> 1, ahalf = (tid & 1) * 16;
    const float* aP = Abuf + (size_t)arow * H_DIM + ahalf;
    short* sAw = sA + arow * 40 + ahalf;
    const short* sXr = sX + fr * 40 + fq * 8;
    const short* sAr = sA + (wn + fr) * 40 + fq * 8;
    for (int kt = 0; kt < H_DIM / 32; ++kt) {
        f32x4 xv = *(const f32x4*)(xP + kt * 32);
        f32x4 a0 = *(const f32x4*)(aP + kt * 32);
        f32x4 a1 = *(const f32x4*)(aP + kt * 32 + 4);
        f32x4 a2 = *(const f32x4*)(aP + kt * 32 + 8);
        f32x4 a3 = *(const f32x4*)(aP + kt * 32 + 12);
        bf16x4 xs;
        xs[0] = f2bf(xv[0]); xs[1] = f2bf(xv[1]);
        xs[2] = f2bf(xv[2]); xs[3] = f2bf(xv[3]);
        bf16x8 as0 = pack8(a0, a1), as1 = pack8(a2, a3);
        __syncthreads();
        *(bf16x4*)(sXw) = xs;
        *(bf16x8*)(sAw) = as0;
        *(bf16x8*)(sAw + 8) = as1;
        __syncthreads();
        bf16x8 xf0 = *(const bf16x8*)(sXr);
        bf16x8 xf1 = *(const bf16x8*)(sXr + 16 * 40);
        bf16x8 af0 = *(const bf16x8*)(sAr);
        bf16x8 af1 = *(const bf16x8*)(sAr + 16 * 40);
        acc[0][0] = __builtin_amdgcn_mfma_f32_16x16x32_bf16(xf0, af0, acc[0][0], 0, 0, 0);
        acc[0][1] = __builtin_amdgcn_mfma_f32_16x16x32_bf16(xf0, af1, acc[0][1], 0, 0, 0);
        acc[1][0] = __builtin_amdgcn_mfma_f32_16x16x32_bf16(xf1, af0, acc[1][0], 0, 0, 0);
        acc[1][1] = __builtin_amdgcn_mfma_f32_16x16x32_bf16(xf1, af1, acc[1][1], 0, 0, 0);
    }
#pragma unroll
    for (int ni = 0; ni < 2; ++ni) {
        const int col = wn + ni * 16 + fr;
#pragma unroll
        for (int mi = 0; mi < 2; ++mi) {
            const int row = m0 + mi * 16 + fq * 4;
#pragma unroll
            for (int r = 0; r < 4; ++r)
                la[(size_t)(row + r) * LA_WIDTH + col] = acc[mi][ni][r];
        }
    }
}

#define LDS_STRIDE 40
__global__ __launch_bounds__(256, 2)
void main_gemm(const float* __restrict__ x, const float* __restrict__ W,
               const float* __restrict__ bias, const float* __restrict__ Bbuf,
               const float* __restrict__ la, float* __restrict__ out) {
    __shared__ __align__(16) short sA[128 * LDS_STRIDE];
    __shared__ __align__(16) short sB[128 * LDS_STRIDE];
    const int tid = threadIdx.x;
    const int n0 = blockIdx.x * 128, m0 = blockIdx.y * 128;
    const int wave = tid >> 6, lane = tid & 63;
    const int wm = (wave & 1) * 64, wn = (wave >> 1) * 64;
    const int fr = lane & 15, fq = lane >> 4;
    f32x4 acc[4][4] = {};
    const int srow = tid >> 1, shalf = (tid & 1) * 16;
    const float* xP = x + (size_t)(m0 + srow) * H_DIM + shalf;
    const int wRow = n0 + srow;
    const bool wValid = wRow < N_DIM;
    const float* wP = W + (size_t)wRow * H_DIM + shalf;
    const int slice = (n0 >= D0_DIM) ? 1 : 0;
    const int oCol = wRow - slice * D0_DIM;
    const bool bValid = wValid && (oCol < (slice ? D1_DIM : D0_DIM));
    const float* laP = la + (size_t)(m0 + srow) * LA_WIDTH + slice * R_DIM + shalf;
    const float* bP = Bbuf + ((size_t)slice * D0_DIM + oCol) * R_DIM + shalf;
    short* sAw = sA + srow * LDS_STRIDE + shalf;
    short* sBw = sB + srow * LDS_STRIDE + shalf;
    const short* sAr = sA + (wm + fr) * LDS_STRIDE + fq * 8;
    const short* sBr = sB + (wn + fr) * LDS_STRIDE + fq * 8;
    const int KT = H_DIM / 32;
    for (int it = 0; it < KT + 2; ++it) {
        const float *pa, *pb;
        bool vb;
        if (it < KT) { pa = xP + it * 32; pb = wP + it * 32; vb = wValid; }
        else { const int lt = it - KT; pa = laP + lt * 32; pb = bP + lt * 32; vb = bValid; }
        f32x4 a0 = *(const f32x4*)(pa);
        f32x4 a1 = *(const f32x4*)(pa + 4);
        f32x4 a2 = *(const f32x4*)(pa + 8);
        f32x4 a3 = *(const f32x4*)(pa + 12);
        f32x4 z = {0.f, 0.f, 0.f, 0.f};
        f32x4 b0 = z, b1 = z, b2 = z, b3 = z;
        if (vb) {
            b0 = *(const f32x4*)(pb); b1 = *(const f32x4*)(pb + 4);
            b2 = *(const f32x4*)(pb + 8); b3 = *(const f32x4*)(pb + 12);
        }
        bf16x8 pa0 = pack8(a0, a1), pa1 = pack8(a2, a3);
        bf16x8 pb0 = pack8(b0, b1), pb1 = pack8(b2, b3);
        __syncthreads();
        *(bf16x8*)(sAw) = pa0; *(bf16x8*)(sAw + 8) = pa1;
        *(bf16x8*)(sBw) = pb0; *(bf16x8*)(sBw + 8) = pb1;
        __syncthreads();
        bf16x8 af[4], bfg[4];
#pragma unroll
        for (int i = 0; i < 4; ++i) af[i] = *(const bf16x8*)(sAr + i * 16 * LDS_STRIDE);
#pragma unroll
        for (int i = 0; i < 4; ++i) bfg[i] = *(const bf16x8*)(sBr + i * 16 * LDS_STRIDE);
#pragma unroll
        for (int mi = 0; mi < 4; ++mi)
#pragma unroll
            for (int ni = 0; ni < 4; ++ni)
                acc[mi][ni] = __builtin_amdgcn_mfma_f32_16x16x32_bf16(
                    af[mi], bfg[ni], acc[mi][ni], 0, 0, 0);
    }
#pragma unroll
    for (int ni = 0; ni < 4; ++ni) {
        const int col = n0 + wn + ni * 16 + fr;
        if (col < N_DIM) {
            const float bv = bias[col];
#pragma unroll
            for (int mi = 0; mi < 4; ++mi) {
                const int row = m0 + wm + mi * 16 + fq * 4;
#pragma unroll
                for (int r = 0; r < 4; ++r)
                    out[(size_t)(row + r) * N_DIM + col] = acc[mi][ni][r] + bv;
            }
        }
    }
}

extern "C" void kernel_launch(void* const* d_in, const int* in_sizes, int n_in,
                              void* d_out, int out_size, void* d_ws, size_t ws_size,
                              hipStream_t stream) {
    const float* x    = (const float*)d_in[0];
    const float* W    = (const float*)d_in[1];
    const float* bias = (const float*)d_in[2];
    const float* A    = (const float*)d_in[3];
    const float* B    = (const float*)d_in[4];
    float* out = (float*)d_out;

    const size_t xe_bytes = (size_t)S_DIM * K_EXT * 2;          // 119,537,664
    const size_t we_bytes = (size_t)N_PAD * K_EXT * 2;          //  31,752,192
    const size_t ae_bytes = (size_t)LA_WIDTH * H_DIM * 2;       //   1,835,008

    if (ws_size >= xe_bytes + we_bytes + ae_bytes) {
        short* xe = (short*)d_ws;
        short* we = (short*)((char*)d_ws + xe_bytes);
        short* ae = (short*)((char*)d_ws + xe_bytes + we_bytes);

        convert_x<<<dim3(S_DIM * 896 / 256), dim3(256), 0, stream>>>(x, xe);
        convert_w<<<dim3(N_DIM * 896 / 256), dim3(256), 0, stream>>>(W, we);
        convert_w_lora<<<dim3(N_DIM * 16 / 256), dim3(256), 0, stream>>>(B, we);
        convert_a<<<dim3(LA_WIDTH * 896 / 256), dim3(256), 0, stream>>>(A, ae);
        lora_a_fast<<<dim3(S_DIM / 32), dim3(256), 0, stream>>>(xe, ae, xe);
        main_gemm_fast<<<dim3(N_PAD / 128, S_DIM / 128), dim3(256), 0, stream>>>(
            xe, we, bias, out);
    } else {
        float* la = (float*)d_ws;   // 4 MB scratch
        lora_a_gemm<<<dim3(S_DIM / 32), dim3(256), 0, stream>>>(x, A, la);
        main_gemm<<<dim3(N_DIM / 128 + 1, S_DIM / 128), dim3(256), 0, stream>>>(
            x, W, bias, B, la, out);
    }
}

// Round 3
// 864.262 us; speedup vs baseline: 1.5347x; 1.1351x over previous
//
#include <hip/hip_runtime.h>
#include <hip/hip_bf16.h>

// Problem constants (from reference)
#define S_DIM 8192
#define H_DIM 7168
#define D0_DIM 1536
#define D1_DIM 576
#define N_DIM 2112          // D0 + D1
#define R_DIM 64
#define LA_WIDTH 128        // 2 * R

// Extended-K fused layout: K' = H + 128 (64 lora cols per slice, complementary
// halves zeroed in Wext so one GEMM computes base + LoRA-B contribution).
#define K_EXT 7296
#define KT64 114            // K_EXT / 64
#define N_PAD 2176          // 17 * 128
#define KSPLIT 8
#define KCHUNK 896          // H_DIM / KSPLIT

typedef __attribute__((ext_vector_type(4))) float f32x4;
typedef __attribute__((ext_vector_type(8))) short bf16x8;
typedef __attribute__((ext_vector_type(4))) short bf16x4;

__device__ __forceinline__ short f2bf(float f) {
    union { __hip_bfloat16 h; short s; } u;
    u.h = __float2bfloat16(f);
    return u.s;
}

__device__ __forceinline__ bf16x8 pack8(f32x4 a, f32x4 b) {
    bf16x8 r;
    r[0] = f2bf(a[0]); r[1] = f2bf(a[1]); r[2] = f2bf(a[2]); r[3] = f2bf(a[3]);
    r[4] = f2bf(b[0]); r[5] = f2bf(b[1]); r[6] = f2bf(b[2]); r[7] = f2bf(b[3]);
    return r;
}

__device__ __forceinline__ void gload_lds16(const short* g, short* l) {
    __builtin_amdgcn_global_load_lds(
        (const __attribute__((address_space(1))) unsigned int*)(const void*)g,
        (__attribute__((address_space(3))) unsigned int*)(void*)l, 16, 0, 0);
}

// ---------------------------------------------------------------------------
// convert_w: W fp32 [N,H] -> Wext bf16 [N_PAD,K_EXT] cols 0..H
// ---------------------------------------------------------------------------
__global__ __launch_bounds__(256)
void convert_w(const float* __restrict__ W, short* __restrict__ we) {
    unsigned id = blockIdx.x * 256u + threadIdx.x;   // < 2112*896
    unsigned row = id / 896u, col = (id % 896u) * 8u;
    const float* p = W + (size_t)row * H_DIM + col;
    f32x4 a = *(const f32x4*)p;
    f32x4 b = *(const f32x4*)(p + 4);
    *(bf16x8*)(we + (size_t)row * K_EXT + col) = pack8(a, b);
}

// convert_w_lora: fill Wext cols H..H+128 per row n:
//   n <  D0: [B0 row n (64), zeros(64)] ; n >= D0: [zeros(64), B1 row n-D0 (64)]
__global__ __launch_bounds__(256)
void convert_w_lora(const float* __restrict__ Bbuf, short* __restrict__ we) {
    unsigned id = blockIdx.x * 256u + threadIdx.x;   // < 2112*16
    unsigned n = id / 16u, c8 = (id % 16u) * 8u;     // c8 in {0..120}
    const bool slice1 = n >= D0_DIM;
    bf16x8 v = {};
    const bool dataHalf = slice1 ? (c8 >= 64u) : (c8 < 64u);
    if (dataHalf) {
        unsigned bi = slice1 ? 1u : 0u;
        unsigned brow = slice1 ? (n - D0_DIM) : n;
        unsigned bcol = slice1 ? (c8 - 64u) : c8;
        const float* p = Bbuf + ((size_t)bi * D0_DIM + brow) * R_DIM + bcol;
        f32x4 a = *(const f32x4*)p;
        f32x4 b = *(const f32x4*)(p + 4);
        v = pack8(a, b);
    }
    *(bf16x8*)(we + (size_t)n * K_EXT + H_DIM + c8) = v;
}

// ---------------------------------------------------------------------------
// lora_a_pass: K-split LoRA-A GEMM with convert_x fused into staging.
// Grid (64 m-tiles, 8 k-chunks). Per block: 128 rows x 896 K, BK=32 (28 iters).
// Reads x,A fp32; converts in-kernel; writes converted x to xe (each (row,k)
// covered exactly once across grid) and fp32 partials [8][S][128] to ws.
// ---------------------------------------------------------------------------
__global__ __launch_bounds__(256, 2)
void lora_a_pass(const float* __restrict__ x, const float* __restrict__ A,
                 float* __restrict__ part, short* __restrict__ xe) {
    __shared__ __align__(16) short sX[128 * 40];
    __shared__ __align__(16) short sA[128 * 40];

    const int tid = threadIdx.x;
    const int m0 = blockIdx.x * 128;
    const int k0 = blockIdx.y * KCHUNK;
    const int wave = tid >> 6, lane = tid & 63;
    const int wm = (wave & 1) * 64, wn = (wave >> 1) * 64;
    const int fr = lane & 15, fq = lane >> 4;

    f32x4 acc[4][4] = {};

    const int srow = tid >> 1, shalf = (tid & 1) * 16;
    const float* xP = x + (size_t)(m0 + srow) * H_DIM + k0 + shalf;
    const float* aP = A + (size_t)srow * H_DIM + k0 + shalf;
    short* xeP = xe + (size_t)(m0 + srow) * K_EXT + k0 + shalf;

    short* sXw = sX + srow * 40 + shalf;
    short* sAw = sA + srow * 40 + shalf;
    const short* sXr = sX + (wm + fr) * 40 + fq * 8;
    const short* sAr = sA + (wn + fr) * 40 + fq * 8;

    for (int it = 0; it < KCHUNK / 32; ++it) {
        const float* px = xP + it * 32;
        const float* pa = aP + it * 32;
        f32x4 x0 = *(const f32x4*)(px);
        f32x4 x1 = *(const f32x4*)(px + 4);
        f32x4 x2 = *(const f32x4*)(px + 8);
        f32x4 x3 = *(const f32x4*)(px + 12);
        f32x4 a0 = *(const f32x4*)(pa);
        f32x4 a1 = *(const f32x4*)(pa + 4);
        f32x4 a2 = *(const f32x4*)(pa + 8);
        f32x4 a3 = *(const f32x4*)(pa + 12);
        bf16x8 px0 = pack8(x0, x1), px1 = pack8(x2, x3);
        bf16x8 pa0 = pack8(a0, a1), pa1 = pack8(a2, a3);

        // fused convert_x: write bf16 x to xe main cols
        *(bf16x8*)(xeP + it * 32) = px0;
        *(bf16x8*)(xeP + it * 32 + 8) = px1;

        __syncthreads();
        *(bf16x8*)(sXw) = px0; *(bf16x8*)(sXw + 8) = px1;
        *(bf16x8*)(sAw) = pa0; *(bf16x8*)(sAw + 8) = pa1;
        __syncthreads();

        bf16x8 af[4], bfg[4];
#pragma unroll
        for (int i = 0; i < 4; ++i) af[i] = *(const bf16x8*)(sXr + i * 16 * 40);
#pragma unroll
        for (int i = 0; i < 4; ++i) bfg[i] = *(const bf16x8*)(sAr + i * 16 * 40);
#pragma unroll
        for (int mi = 0; mi < 4; ++mi)
#pragma unroll
            for (int ni = 0; ni < 4; ++ni)
                acc[mi][ni] = __builtin_amdgcn_mfma_f32_16x16x32_bf16(
                    af[mi], bfg[ni], acc[mi][ni], 0, 0, 0);
    }

    // partials: part[kz][row][col] fp32
    float* pBase = part + (size_t)blockIdx.y * S_DIM * LA_WIDTH;
#pragma unroll
    for (int ni = 0; ni < 4; ++ni) {
        const int col = wn + ni * 16 + fr;
#pragma unroll
        for (int mi = 0; mi < 4; ++mi) {
            const int row = m0 + wm + mi * 16 + fq * 4;
#pragma unroll
            for (int r = 0; r < 4; ++r)
                pBase[(size_t)(row + r) * LA_WIDTH + col] = acc[mi][ni][r];
        }
    }
}

// lora_reduce: la = sum of 8 partials -> bf16 -> xe cols H..H+128
__global__ __launch_bounds__(256)
void lora_reduce(const float* __restrict__ part, short* __restrict__ xe) {
    unsigned id = blockIdx.x * 256u + threadIdx.x;   // < 8192*16
    unsigned row = id >> 4, c8 = (id & 15u) * 8u;
    f32x4 s0 = {}, s1 = {};
#pragma unroll
    for (int kz = 0; kz < KSPLIT; ++kz) {
        const float* p = part + ((size_t)kz * S_DIM + row) * LA_WIDTH + c8;
        s0 += *(const f32x4*)(p);
        s1 += *(const f32x4*)(p + 4);
    }
    *(bf16x8*)(xe + (size_t)row * K_EXT + H_DIM + c8) = pack8(s0, s1);
}

// ---------------------------------------------------------------------------
// main_gemm_fast: out = xext @ Wext^T + bias  (K = 7296 includes LoRA-B)
// BK=64 (2 x 32-chunks per barrier, chunk-major LDS [2][128][32]), 128x128
// tile, global_load_lds width 16. Band-swizzled 1D grid: bands of 16 m-tiles,
// n-fast within band (concurrent working set ~62 MB << LLC).
// ---------------------------------------------------------------------------
__global__ __launch_bounds__(256, 3)
void main_gemm_fast(const short* __restrict__ xe, const short* __restrict__ we,
                    const float* __restrict__ bias, float* __restrict__ out) {
    __shared__ __align__(16) short sX[2 * 128 * 32];
    __shared__ __align__(16) short sW[2 * 128 * 32];

    const int tid = threadIdx.x;
    const int b = blockIdx.x;                 // 0..1087
    const int band = b / (17 * 16);
    const int rr = b % (17 * 16);
    const int n0 = (rr % 17) * 128;
    const int m0 = (band * 16 + rr / 17) * 128;

    const int wave = tid >> 6, lane = tid & 63;
    const int wm = (wave & 1) * 64, wn = (wave >> 1) * 64;
    const int fr = lane & 15, fq = lane >> 4;

    f32x4 acc[4][4] = {};

    // DMA mapping: instr (j,c): rows 32*wave+16*j .. +15 of chunk c.
    // lane l -> row +=(l>>2), global col c*32+(l&3)*8; LDS linear = base + l*16B.
    const int lrow = lane >> 2;
    const int lc8 = (lane & 3) * 8;
    const short* gx[2][2];
    const short* gw[2][2];
    short* lx[2][2];
    short* lw[2][2];
#pragma unroll
    for (int j = 0; j < 2; ++j)
#pragma unroll
        for (int c = 0; c < 2; ++c) {
            const int row = 32 * wave + 16 * j + lrow;
            gx[j][c] = xe + (size_t)(m0 + row) * K_EXT + c * 32 + lc8;
            gw[j][c] = we + (size_t)(n0 + row) * K_EXT + c * 32 + lc8;
            lx[j][c] = sX + c * 4096 + (2 * wave + j) * 512;
            lw[j][c] = sW + c * 4096 + (2 * wave + j) * 512;
        }

    const short* sXr = sX + (wm + fr) * 32 + fq * 8;
    const short* sWr = sW + (wn + fr) * 32 + fq * 8;

    for (int kt = 0; kt < KT64; ++kt) {
        const int ko = kt * 64;
        __syncthreads();                       // prev tile's ds_reads complete
#pragma unroll
        for (int j = 0; j < 2; ++j)
#pragma unroll
            for (int c = 0; c < 2; ++c) {
                gload_lds16(gx[j][c] + ko, lx[j][c]);
                gload_lds16(gw[j][c] + ko, lw[j][c]);
            }
        __syncthreads();                       // drains vmcnt -> tile in LDS

#pragma unroll
        for (int c = 0; c < 2; ++c) {
            bf16x8 af[4], bfg[4];
#pragma unroll
            for (int i = 0; i < 4; ++i)
                af[i] = *(const bf16x8*)(sXr + c * 4096 + i * 16 * 32);
#pragma unroll
            for (int i = 0; i < 4; ++i)
                bfg[i] = *(const bf16x8*)(sWr + c * 4096 + i * 16 * 32);
#pragma unroll
            for (int mi = 0; mi < 4; ++mi)
#pragma unroll
                for (int ni = 0; ni < 4; ++ni)
                    acc[mi][ni] = __builtin_amdgcn_mfma_f32_16x16x32_bf16(
                        af[mi], bfg[ni], acc[mi][ni], 0, 0, 0);
        }
    }

    // epilogue: + bias, fp32 store. C/D: col = lane&15, row = fq*4 + r
#pragma unroll
    for (int ni = 0; ni < 4; ++ni) {
        const int col = n0 + wn + ni * 16 + fr;
        if (col < N_DIM) {
            const float bv = bias[col];
#pragma unroll
            for (int mi = 0; mi < 4; ++mi) {
                const int row = m0 + wm + mi * 16 + fq * 4;
#pragma unroll
                for (int r = 0; r < 4; ++r)
                    out[(size_t)(row + r) * N_DIM + col] = acc[mi][ni][r] + bv;
            }
        }
    }
}

// ===========================================================================
// Fallback (round-1 proven path) if workspace is too small for bf16 staging
// ===========================================================================
__global__ __launch_bounds__(256, 2)
void lora_a_gemm(const float* __restrict__ x, const float* __restrict__ Abuf,
                 float* __restrict__ la) {
    __shared__ __align__(16) short sX[32 * 40];
    __shared__ __align__(16) short sA[128 * 40];
    const int tid = threadIdx.x;
    const int m0 = blockIdx.x * 32;
    const int wave = tid >> 6, lane = tid & 63;
    const int fr = lane & 15, fq = lane >> 4;
    const int wn = wave * 32;
    f32x4 acc[2][2] = {};
    const int xrow = tid >> 3, xcol = (tid & 7) * 4;
    const float* xP = x + (size_t)(m0 + xrow) * H_DIM + xcol;
    short* sXw = sX + xrow * 40 + xcol;
    const int arow = tid >> 1, ahalf = (tid & 1) * 16;
    const float* aP = Abuf + (size_t)arow * H_DIM + ahalf;
    short* sAw = sA + arow * 40 + ahalf;
    const short* sXr = sX + fr * 40 + fq * 8;
    const short* sAr = sA + (wn + fr) * 40 + fq * 8;
    for (int kt = 0; kt < H_DIM / 32; ++kt) {
        f32x4 xv = *(const f32x4*)(xP + kt * 32);
        f32x4 a0 = *(const f32x4*)(aP + kt * 32);
        f32x4 a1 = *(const f32x4*)(aP + kt * 32 + 4);
        f32x4 a2 = *(const f32x4*)(aP + kt * 32 + 8);
        f32x4 a3 = *(const f32x4*)(aP + kt * 32 + 12);
        bf16x4 xs;
        xs[0] = f2bf(xv[0]); xs[1] = f2bf(xv[1]);
        xs[2] = f2bf(xv[2]); xs[3] = f2bf(xv[3]);
        bf16x8 as0 = pack8(a0, a1), as1 = pack8(a2, a3);
        __syncthreads();
        *(bf16x4*)(sXw) = xs;
        *(bf16x8*)(sAw) = as0;
        *(bf16x8*)(sAw + 8) = as1;
        __syncthreads();
        bf16x8 xf0 = *(const bf16x8*)(sXr);
        bf16x8 xf1 = *(const bf16x8*)(sXr + 16 * 40);
        bf16x8 af0 = *(const bf16x8*)(sAr);
        bf16x8 af1 = *(const bf16x8*)(sAr + 16 * 40);
        acc[0][0] = __builtin_amdgcn_mfma_f32_16x16x32_bf16(xf0, af0, acc[0][0], 0, 0, 0);
        acc[0][1] = __builtin_amdgcn_mfma_f32_16x16x32_bf16(xf0, af1, acc[0][1], 0, 0, 0);
        acc[1][0] = __builtin_amdgcn_mfma_f32_16x16x32_bf16(xf1, af0, acc[1][0], 0, 0, 0);
        acc[1][1] = __builtin_amdgcn_mfma_f32_16x16x32_bf16(xf1, af1, acc[1][1], 0, 0, 0);
    }
#pragma unroll
    for (int ni = 0; ni < 2; ++ni) {
        const int col = wn + ni * 16 + fr;
#pragma unroll
        for (int mi = 0; mi < 2; ++mi) {
            const int row = m0 + mi * 16 + fq * 4;
#pragma unroll
            for (int r = 0; r < 4; ++r)
                la[(size_t)(row + r) * LA_WIDTH + col] = acc[mi][ni][r];
        }
    }
}

#define LDS_STRIDE 40
__global__ __launch_bounds__(256, 2)
void main_gemm(const float* __restrict__ x, const float* __restrict__ W,
               const float* __restrict__ bias, const float* __restrict__ Bbuf,
               const float* __restrict__ la, float* __restrict__ out) {
    __shared__ __align__(16) short sA[128 * LDS_STRIDE];
    __shared__ __align__(16) short sB[128 * LDS_STRIDE];
    const int tid = threadIdx.x;
    const int n0 = blockIdx.x * 128, m0 = blockIdx.y * 128;
    const int wave = tid >> 6, lane = tid & 63;
    const int wm = (wave & 1) * 64, wn = (wave >> 1) * 64;
    const int fr = lane & 15, fq = lane >> 4;
    f32x4 acc[4][4] = {};
    const int srow = tid >> 1, shalf = (tid & 1) * 16;
    const float* xP = x + (size_t)(m0 + srow) * H_DIM + shalf;
    const int wRow = n0 + srow;
    const bool wValid = wRow < N_DIM;
    const float* wP = W + (size_t)wRow * H_DIM + shalf;
    const int slice = (n0 >= D0_DIM) ? 1 : 0;
    const int oCol = wRow - slice * D0_DIM;
    const bool bValid = wValid && (oCol < (slice ? D1_DIM : D0_DIM));
    const float* laP = la + (size_t)(m0 + srow) * LA_WIDTH + slice * R_DIM + shalf;
    const float* bP = Bbuf + ((size_t)slice * D0_DIM + oCol) * R_DIM + shalf;
    short* sAw = sA + srow * LDS_STRIDE + shalf;
    short* sBw = sB + srow * LDS_STRIDE + shalf;
    const short* sAr = sA + (wm + fr) * LDS_STRIDE + fq * 8;
    const short* sBr = sB + (wn + fr) * LDS_STRIDE + fq * 8;
    const int KT = H_DIM / 32;
    for (int it = 0; it < KT + 2; ++it) {
        const float *pa, *pb;
        bool vb;
        if (it < KT) { pa = xP + it * 32; pb = wP + it * 32; vb = wValid; }
        else { const int lt = it - KT; pa = laP + lt * 32; pb = bP + lt * 32; vb = bValid; }
        f32x4 a0 = *(const f32x4*)(pa);
        f32x4 a1 = *(const f32x4*)(pa + 4);
        f32x4 a2 = *(const f32x4*)(pa + 8);
        f32x4 a3 = *(const f32x4*)(pa + 12);
        f32x4 z = {0.f, 0.f, 0.f, 0.f};
        f32x4 b0 = z, b1 = z, b2 = z, b3 = z;
        if (vb) {
            b0 = *(const f32x4*)(pb); b1 = *(const f32x4*)(pb + 4);
            b2 = *(const f32x4*)(pb + 8); b3 = *(const f32x4*)(pb + 12);
        }
        bf16x8 pa0 = pack8(a0, a1), pa1 = pack8(a2, a3);
        bf16x8 pb0 = pack8(b0, b1), pb1 = pack8(b2, b3);
        __syncthreads();
        *(bf16x8*)(sAw) = pa0; *(bf16x8*)(sAw + 8) = pa1;
        *(bf16x8*)(sBw) = pb0; *(bf16x8*)(sBw + 8) = pb1;
        __syncthreads();
        bf16x8 af[4], bfg[4];
#pragma unroll
        for (int i = 0; i < 4; ++i) af[i] = *(const bf16x8*)(sAr + i * 16 * LDS_STRIDE);
#pragma unroll
        for (int i = 0; i < 4; ++i) bfg[i] = *(const bf16x8*)(sBr + i * 16 * LDS_STRIDE);
#pragma unroll
        for (int mi = 0; mi < 4; ++mi)
#pragma unroll
            for (int ni = 0; ni < 4; ++ni)
                acc[mi][ni] = __builtin_amdgcn_mfma_f32_16x16x32_bf16(
                    af[mi], bfg[ni], acc[mi][ni], 0, 0, 0);
    }
#pragma unroll
    for (int ni = 0; ni < 4; ++ni) {
        const int col = n0 + wn + ni * 16 + fr;
        if (col < N_DIM) {
            const float bv = bias[col];
#pragma unroll
            for (int mi = 0; mi < 4; ++mi) {
                const int row = m0 + wm + mi * 16 + fq * 4;
#pragma unroll
                for (int r = 0; r < 4; ++r)
                    out[(size_t)(row + r) * N_DIM + col] = acc[mi][ni][r] + bv;
            }
        }
    }
}

extern "C" void kernel_launch(void* const* d_in, const int* in_sizes, int n_in,
                              void* d_out, int out_size, void* d_ws, size_t ws_size,
                              hipStream_t stream) {
    const float* x    = (const float*)d_in[0];
    const float* W    = (const float*)d_in[1];
    const float* bias = (const float*)d_in[2];
    const float* A    = (const float*)d_in[3];
    const float* B    = (const float*)d_in[4];
    float* out = (float*)d_out;

    const size_t xe_bytes   = (size_t)S_DIM * K_EXT * 2;              // 119,537,664
    const size_t we_bytes   = (size_t)N_PAD * K_EXT * 2;              //  31,752,192
    const size_t part_bytes = (size_t)KSPLIT * S_DIM * LA_WIDTH * 4;  //  33,554,432
    const size_t tail = (we_bytes > part_bytes) ? we_bytes : part_bytes;

    if (ws_size >= xe_bytes + tail) {
        short* xe = (short*)d_ws;
        short* we = (short*)((char*)d_ws + xe_bytes);
        float* part = (float*)((char*)d_ws + xe_bytes);  // overlaps we: consumed
                                                         // by lora_reduce before
                                                         // convert_w writes we

        lora_a_pass<<<dim3(S_DIM / 128, KSPLIT), dim3(256), 0, stream>>>(x, A, part, xe);
        lora_reduce<<<dim3(S_DIM * 16 / 256), dim3(256), 0, stream>>>(part, xe);
        convert_w<<<dim3(N_DIM * 896 / 256), dim3(256), 0, stream>>>(W, we);
        convert_w_lora<<<dim3(N_DIM * 16 / 256), dim3(256), 0, stream>>>(B, we);
        main_gemm_fast<<<dim3(17 * 64), dim3(256), 0, stream>>>(xe, we, bias, out);
    } else {
        float* la = (float*)d_ws;   // 4 MB scratch
        lora_a_gemm<<<dim3(S_DIM / 32), dim3(256), 0, stream>>>(x, A, la);
        main_gemm<<<dim3(N_DIM / 128 + 1, S_DIM / 128), dim3(256), 0, stream>>>(
            x, W, bias, B, la, out);
    }
}